// Round 1
// baseline (1075.197 us; speedup 1.0000x reference)
//
#include <hip/hip_runtime.h>

#define D 32

// ---------------------------------------------------------------------------
// K1: src_feat = feat @ Ws^T ; dst_feat = feat @ Wd^T + bd
// 8 nodes per 256-thread block; thread (nl, d) computes one output element.
// Weights staged TRANSPOSED in LDS so lane d reads bank d (conflict-free).
// ---------------------------------------------------------------------------
__global__ __launch_bounds__(256) void k_node_transform(
    const float* __restrict__ feat, const float* __restrict__ Ws,
    const float* __restrict__ Wd, const float* __restrict__ bd,
    float* __restrict__ src_feat, float* __restrict__ dst_feat, int N)
{
    __shared__ float WsT[D * D];
    __shared__ float WdT[D * D];
    __shared__ float bdS[D];
    __shared__ float fS[8][D];

    const int t = threadIdx.x;
    for (int i = t; i < D * D; i += 256) {
        const int d = i >> 5, k = i & 31;
        WsT[k * D + d] = Ws[i];
        WdT[k * D + d] = Wd[i];
    }
    if (t < D) bdS[t] = bd[t];

    const int nodeBase = blockIdx.x * 8;
    {
        const int n = nodeBase + (t >> 5);
        fS[t >> 5][t & 31] = (n < N) ? feat[nodeBase * D + t] : 0.f;
    }
    __syncthreads();

    const int nl = t >> 5, d = t & 31;
    const int n = nodeBase + nl;
    if (n >= N) return;

    float accS = 0.f, accD = bdS[d];
#pragma unroll
    for (int k = 0; k < D; ++k) {
        const float f = fS[nl][k];
        accS += f * WsT[k * D + d];
        accD += f * WdT[k * D + d];
    }
    src_feat[n * D + d] = accS;
    dst_feat[n * D + d] = accD;
}

// ---------------------------------------------------------------------------
// K2: agg[v] += src_feat[u] + dst_feat[v]  for every edge (u->v).
// (Equivalent to segment_sum(src_feat[src]) + deg*dst_feat — deg folded away.)
// One thread per edge-quarter (4 floats): float4 gathers + 4 scalar atomics.
// ---------------------------------------------------------------------------
__global__ __launch_bounds__(256) void k_scatter(
    const int* __restrict__ src, const int* __restrict__ dst,
    const float* __restrict__ src_feat, const float* __restrict__ dst_feat,
    float* __restrict__ agg, int E)
{
    const long g = (long)blockIdx.x * 256 + threadIdx.x;
    const int e = (int)(g >> 3);
    if (e >= E) return;
    const int q = (int)(g & 7);

    const int u = src[e], v = dst[e];
    const float4 a = *(const float4*)(src_feat + u * D + q * 4);
    const float4 b = *(const float4*)(dst_feat + v * D + q * 4);
    float* p = agg + v * D + q * 4;
    atomicAdd(p + 0, a.x + b.x);
    atomicAdd(p + 1, a.y + b.y);
    atomicAdd(p + 2, a.z + b.z);
    atomicAdd(p + 3, a.w + b.w);
}

// ---------------------------------------------------------------------------
// K3: out = agg @ Wr^T + br ; src2 = out @ Ws^T ; dst2 = out @ Wd^T + bd.
// Same structure as K1 with an extra LDS round-trip for the intermediate row.
// ---------------------------------------------------------------------------
__global__ __launch_bounds__(256) void k_out_transform(
    const float* __restrict__ agg,
    const float* __restrict__ Ws, const float* __restrict__ Wd,
    const float* __restrict__ bd, const float* __restrict__ Wr,
    const float* __restrict__ br,
    float* __restrict__ src2, float* __restrict__ dst2, int N)
{
    __shared__ float WsT[D * D];
    __shared__ float WdT[D * D];
    __shared__ float WrT[D * D];
    __shared__ float bdS[D], brS[D];
    __shared__ float aS[8][D];
    __shared__ float oS[8][D];

    const int t = threadIdx.x;
    for (int i = t; i < D * D; i += 256) {
        const int d = i >> 5, k = i & 31;
        WsT[k * D + d] = Ws[i];
        WdT[k * D + d] = Wd[i];
        WrT[k * D + d] = Wr[i];
    }
    if (t < D) { bdS[t] = bd[t]; brS[t] = br[t]; }

    const int nodeBase = blockIdx.x * 8;
    {
        const int n = nodeBase + (t >> 5);
        aS[t >> 5][t & 31] = (n < N) ? agg[nodeBase * D + t] : 0.f;
    }
    __syncthreads();

    const int nl = t >> 5, d = t & 31;
    float o = brS[d];
#pragma unroll
    for (int k = 0; k < D; ++k) o += aS[nl][k] * WrT[k * D + d];
    oS[nl][d] = o;
    __syncthreads();

    const int n = nodeBase + nl;
    if (n >= N) return;
    float s = 0.f, dd = bdS[d];
#pragma unroll
    for (int k = 0; k < D; ++k) {
        const float ov = oS[nl][k];
        s += ov * WsT[k * D + d];
        dd += ov * WdT[k * D + d];
    }
    src2[n * D + d] = s;
    dst2[n * D + d] = dd;
}

// ---------------------------------------------------------------------------
// K4: out[e] = src2[src[e]] + dst2[dst[e]]   ([E, 32] f32, coalesced float4)
// ---------------------------------------------------------------------------
__global__ __launch_bounds__(256) void k_gather_out(
    const int* __restrict__ src, const int* __restrict__ dst,
    const float* __restrict__ src2, const float* __restrict__ dst2,
    float* __restrict__ out, int E)
{
    const long g = (long)blockIdx.x * 256 + threadIdx.x;
    const int e = (int)(g >> 3);
    if (e >= E) return;
    const int q = (int)(g & 7);

    const int u = src[e], v = dst[e];
    const float4 a = *(const float4*)(src2 + u * D + q * 4);
    const float4 b = *(const float4*)(dst2 + v * D + q * 4);
    float4 r;
    r.x = a.x + b.x; r.y = a.y + b.y; r.z = a.z + b.z; r.w = a.w + b.w;
    *(float4*)(out + (long)e * D + q * 4) = r;
}

extern "C" void kernel_launch(void* const* d_in, const int* in_sizes, int n_in,
                              void* d_out, int out_size, void* d_ws, size_t ws_size,
                              hipStream_t stream)
{
    const float* feat = (const float*)d_in[0];
    const int*   src  = (const int*)d_in[1];
    const int*   dst  = (const int*)d_in[2];
    const float* Ws   = (const float*)d_in[3];
    const float* Wd   = (const float*)d_in[4];
    const float* bd   = (const float*)d_in[5];
    const float* Wr   = (const float*)d_in[6];
    const float* br   = (const float*)d_in[7];
    float* out = (float*)d_out;

    const int N = in_sizes[0] / D;
    const int E = in_sizes[1];

    const size_t nodeBytes = (size_t)N * D * sizeof(float);
    float* src_feat = (float*)d_ws;
    float* dst_feat = (float*)((char*)d_ws + nodeBytes);
    float* agg      = (float*)((char*)d_ws + 2 * nodeBytes);
    float* src2 = src_feat;  // dead after K2 -> reuse
    float* dst2 = dst_feat;

    hipMemsetAsync(agg, 0, nodeBytes, stream);  // d_ws is re-poisoned each launch

    const int nodeBlocks = (N + 7) / 8;
    k_node_transform<<<nodeBlocks, 256, 0, stream>>>(feat, Ws, Wd, bd,
                                                     src_feat, dst_feat, N);

    const long eThreads = (long)E * 8;
    const int edgeBlocks = (int)((eThreads + 255) / 256);
    k_scatter<<<edgeBlocks, 256, 0, stream>>>(src, dst, src_feat, dst_feat, agg, E);

    k_out_transform<<<nodeBlocks, 256, 0, stream>>>(agg, Ws, Wd, bd, Wr, br,
                                                    src2, dst2, N);

    k_gather_out<<<edgeBlocks, 256, 0, stream>>>(src, dst, src2, dst2, out, E);
}

// Round 2
// 654.543 us; speedup vs baseline: 1.6427x; 1.6427x over previous
//
#include <hip/hip_runtime.h>

#define D 32
#define SCHUNK 1024

// ---------------------------------------------------------------------------
// K1: src_feat = feat @ Ws^T ; dst_feat = feat @ Wd^T + bd
// 8 nodes per 256-thread block; thread (nl, d) computes one output element.
// Weights staged TRANSPOSED in LDS so lane d reads bank d (conflict-free).
// ---------------------------------------------------------------------------
__global__ __launch_bounds__(256) void k_node_transform(
    const float* __restrict__ feat, const float* __restrict__ Ws,
    const float* __restrict__ Wd, const float* __restrict__ bd,
    float* __restrict__ src_feat, float* __restrict__ dst_feat, int N)
{
    __shared__ float WsT[D * D];
    __shared__ float WdT[D * D];
    __shared__ float bdS[D];
    __shared__ float fS[8][D];

    const int t = threadIdx.x;
    for (int i = t; i < D * D; i += 256) {
        const int d = i >> 5, k = i & 31;
        WsT[k * D + d] = Ws[i];
        WdT[k * D + d] = Wd[i];
    }
    if (t < D) bdS[t] = bd[t];

    const int nodeBase = blockIdx.x * 8;
    {
        const int n = nodeBase + (t >> 5);
        fS[t >> 5][t & 31] = (n < N) ? feat[nodeBase * D + t] : 0.f;
    }
    __syncthreads();

    const int nl = t >> 5, d = t & 31;
    const int n = nodeBase + nl;
    if (n >= N) return;

    float accS = 0.f, accD = bdS[d];
#pragma unroll
    for (int k = 0; k < D; ++k) {
        const float f = fS[nl][k];
        accS += f * WsT[k * D + d];
        accD += f * WdT[k * D + d];
    }
    src_feat[n * D + d] = accS;
    dst_feat[n * D + d] = accD;
}

// ---------------------------------------------------------------------------
// Counting sort by dst: histogram -> scan -> scatter src ids.
// ---------------------------------------------------------------------------
__global__ __launch_bounds__(256) void k_hist(
    const int* __restrict__ dst, int* __restrict__ deg, int E)
{
    const int e = blockIdx.x * 256 + threadIdx.x;
    if (e < E) atomicAdd(&deg[dst[e]], 1);
}

// Per-1024-chunk exclusive scan (Hillis-Steele, ping-pong LDS).
__global__ __launch_bounds__(256) void k_scan1(
    const int* __restrict__ deg, int* __restrict__ offset,
    int* __restrict__ blockSums, int N)
{
    __shared__ int buf[2][SCHUNK];
    const int t = threadIdx.x;
    const int base = blockIdx.x * SCHUNK;
    for (int j = t; j < SCHUNK; j += 256)
        buf[0][j] = (base + j < N) ? deg[base + j] : 0;
    __syncthreads();
    int pin = 0;
    for (int off = 1; off < SCHUNK; off <<= 1) {
        for (int j = t; j < SCHUNK; j += 256)
            buf[pin ^ 1][j] = buf[pin][j] + (j >= off ? buf[pin][j - off] : 0);
        __syncthreads();
        pin ^= 1;
    }
    for (int j = t; j < SCHUNK; j += 256)
        if (base + j < N) offset[base + j] = (j > 0) ? buf[pin][j - 1] : 0;
    if (t == 0) blockSums[blockIdx.x] = buf[pin][SCHUNK - 1];
}

// Tiny serial exclusive scan over the ~98 block sums.
__global__ __launch_bounds__(64) void k_scan2(int* __restrict__ bs, int nb)
{
    if (threadIdx.x == 0) {
        int run = 0;
        for (int i = 0; i < nb; ++i) { const int v = bs[i]; bs[i] = run; run += v; }
    }
}

__global__ __launch_bounds__(256) void k_scan3(
    int* __restrict__ offset, int* __restrict__ cursor,
    const int* __restrict__ blockSums, int N)
{
    const int i = blockIdx.x * 256 + threadIdx.x;
    if (i < N) {
        const int o = offset[i] + blockSums[i >> 10];
        offset[i] = o;
        cursor[i] = o;
    }
}

__global__ __launch_bounds__(256) void k_scatter_ids(
    const int* __restrict__ src, const int* __restrict__ dst,
    int* __restrict__ cursor, int* __restrict__ edge_src, int E)
{
    const int e = blockIdx.x * 256 + threadIdx.x;
    if (e < E) {
        const int slot = atomicAdd(&cursor[dst[e]], 1);
        edge_src[slot] = src[e];
    }
}

// ---------------------------------------------------------------------------
// Fused: agg[n] = sum_{u in edges(n)} src_feat[u] + deg[n]*dst_feat[n]
//        out = agg@Wr^T+br ; src2 = out@Ws^T ; dst2 = out@Wd^T+bd
// 8 nodes / 256-thread block; group (nl) of 32 lanes owns one node row.
// Gather reads are coalesced 128B rows of L3-resident src_feat; no atomics.
// ---------------------------------------------------------------------------
__global__ __launch_bounds__(256) void k_agg_fused(
    const int* __restrict__ edge_src, const int* __restrict__ offset,
    const int* __restrict__ deg,
    const float* __restrict__ src_feat, const float* __restrict__ dst_feat,
    const float* __restrict__ Ws, const float* __restrict__ Wd,
    const float* __restrict__ bd, const float* __restrict__ Wr,
    const float* __restrict__ br,
    float* __restrict__ src2, float* __restrict__ dst2, int N)
{
    __shared__ float WsT[D * D];
    __shared__ float WdT[D * D];
    __shared__ float WrT[D * D];
    __shared__ float bdS[D], brS[D];
    __shared__ float aS[8][D];
    __shared__ float oS[8][D];

    const int t = threadIdx.x;
    for (int i = t; i < D * D; i += 256) {
        const int d = i >> 5, k = i & 31;
        WsT[k * D + d] = Ws[i];
        WdT[k * D + d] = Wd[i];
        WrT[k * D + d] = Wr[i];
    }
    if (t < D) { bdS[t] = bd[t]; brS[t] = br[t]; }

    const int nl = t >> 5, d = t & 31;
    const int n = blockIdx.x * 8 + nl;

    float acc = 0.f;
    if (n < N) {
        const int off = offset[n];
        const int dg  = deg[n];
        for (int i = 0; i < dg; ++i) {
            const int u = edge_src[off + i];
            acc += src_feat[u * D + d];
        }
        acc += (float)dg * dst_feat[n * D + d];
    }
    __syncthreads();              // weights + biases staged

    aS[nl][d] = acc;
    __syncthreads();

    float o = brS[d];
#pragma unroll
    for (int k = 0; k < D; ++k) o += aS[nl][k] * WrT[k * D + d];
    oS[nl][d] = o;
    __syncthreads();

    if (n >= N) return;
    float s = 0.f, dd = bdS[d];
#pragma unroll
    for (int k = 0; k < D; ++k) {
        const float ov = oS[nl][k];
        s  += ov * WsT[k * D + d];
        dd += ov * WdT[k * D + d];
    }
    src2[n * D + d] = s;
    dst2[n * D + d] = dd;
}

// ---------------------------------------------------------------------------
// K4: out[e] = src2[src[e]] + dst2[dst[e]]   ([E, 32] f32, coalesced float4)
// ---------------------------------------------------------------------------
__global__ __launch_bounds__(256) void k_gather_out(
    const int* __restrict__ src, const int* __restrict__ dst,
    const float* __restrict__ src2, const float* __restrict__ dst2,
    float* __restrict__ out, int E)
{
    const long g = (long)blockIdx.x * 256 + threadIdx.x;
    const int e = (int)(g >> 3);
    if (e >= E) return;
    const int q = (int)(g & 7);

    const int u = src[e], v = dst[e];
    const float4 a = *(const float4*)(src2 + u * D + q * 4);
    const float4 b = *(const float4*)(dst2 + v * D + q * 4);
    float4 r;
    r.x = a.x + b.x; r.y = a.y + b.y; r.z = a.z + b.z; r.w = a.w + b.w;
    *(float4*)(out + (long)e * D + q * 4) = r;
}

extern "C" void kernel_launch(void* const* d_in, const int* in_sizes, int n_in,
                              void* d_out, int out_size, void* d_ws, size_t ws_size,
                              hipStream_t stream)
{
    const float* feat = (const float*)d_in[0];
    const int*   src  = (const int*)d_in[1];
    const int*   dst  = (const int*)d_in[2];
    const float* Ws   = (const float*)d_in[3];
    const float* Wd   = (const float*)d_in[4];
    const float* bd   = (const float*)d_in[5];
    const float* Wr   = (const float*)d_in[6];
    const float* br   = (const float*)d_in[7];
    float* out = (float*)d_out;

    const int N = in_sizes[0] / D;
    const int E = in_sizes[1];

    const size_t nodeBytes = (size_t)N * D * sizeof(float);

    // --- scratch layout ---
    // Everything consumed BEFORE the final kernel lives at the front of d_out
    // (204.8 MB; the final kernel overwrites all of it). Only src2/dst2 (read
    // concurrently with the final out-writes) live in d_ws.
    char* ob = (char*)d_out;
    float* src_feat = (float*)ob;                                  // 12.8 MB
    float* dst_feat = (float*)(ob + nodeBytes);                    // 12.8 MB
    int*   edge_src = (int*)(ob + 2 * nodeBytes);                  //  6.4 MB
    int*   deg      = (int*)(ob + 2 * nodeBytes + (size_t)E * 4);  //  0.4 MB
    int*   offset   = deg + N;                                     //  0.4 MB
    int*   cursor   = offset + N;                                  //  0.4 MB
    int*   blockSums= cursor + N;                                  //  tiny

    float* src2 = (float*)d_ws;
    float* dst2 = (float*)((char*)d_ws + nodeBytes);

    const int nodeBlocks = (N + 7) / 8;
    const int edgeThreadBlocks = (E + 255) / 256;
    const int nBlocks256 = (N + 255) / 256;
    const int nbScan = (N + SCHUNK - 1) / SCHUNK;

    hipMemsetAsync(deg, 0, (size_t)N * sizeof(int), stream);

    k_node_transform<<<nodeBlocks, 256, 0, stream>>>(feat, Ws, Wd, bd,
                                                     src_feat, dst_feat, N);

    k_hist<<<edgeThreadBlocks, 256, 0, stream>>>(dst, deg, E);
    k_scan1<<<nbScan, 256, 0, stream>>>(deg, offset, blockSums, N);
    k_scan2<<<1, 64, 0, stream>>>(blockSums, nbScan);
    k_scan3<<<nBlocks256, 256, 0, stream>>>(offset, cursor, blockSums, N);
    k_scatter_ids<<<edgeThreadBlocks, 256, 0, stream>>>(src, dst, cursor,
                                                        edge_src, E);

    k_agg_fused<<<nodeBlocks, 256, 0, stream>>>(edge_src, offset, deg,
                                                src_feat, dst_feat,
                                                Ws, Wd, bd, Wr, br,
                                                src2, dst2, N);

    const long outThreads = (long)E * 8;
    const int outBlocks = (int)((outThreads + 255) / 256);
    k_gather_out<<<outBlocks, 256, 0, stream>>>(src, dst, src2, dst2, out, E);
}